// Round 7
// baseline (335.664 us; speedup 1.0000x reference)
//
#include <hip/hip_runtime.h>

// LinkPredictor: score[e] = w2 . relu(W1 . concat(h[src[e]], h[dst[e]]) + b1) + b2
// N_NODES=100000, N_EDGES=1600000, D=128, HIDDEN=256
//
// R19: shrink the non-edge tail (edge pass is at its pattern floor).
//   R18 post-mortem: edge = 155 us @ FETCH 530 MB = 96% of the (5x-confirmed)
//   ~3.55 TB/s L2-miss service model; Us ~51 (compulsory) + pk 13 + Ud ~465
//   (irreducible random degree-16 gather: 2-D bucketing raises Ud to ~700 MB,
//   dst-XCD routing raises Us to ~350 MB -- no exact-math lever left).
//   Changes:
//   (1) u_gemm4: row-tile 64->128 (32 KB LDS, 8 gload_lds/thread, 32 MFMA,
//       acc[8][2], lb(256,3)) -- gemm was latency-bound (60 us vs 21 us
//       traffic), halve block count, 2x work per DMA barrier. Predict ~42.
//   (2) hist fused into cvt as tail blocks, ATOMIC-FREE: block k writes
//       cnt[k][49] plain stores; scatter rebuilds prefixes from cnt (50 KB,
//       L2-hot). One fewer dispatch, no gh zeroing.
//   (3) Order: cvt+hist -> gemm -> scatter -> edge -> unscatter (rank
//       aliases hbf, so scatter stays after gemm). 5 dispatches.
//   Predict total 335 -> ~310. Falsifier: gemm >=55 us or VGPR>200 -> revert.

#define NNODES 100000
#define E_TOTAL 1600000
#define D 128
#define K2 256
#define H 256
#define NB2 49                       // ceil(100000/2048) coarse src buckets
#define EDGE_GRID 3125               // 3125 blk * 16 grp * 8 chunks * 4 edges = 1.6M
#define SORT_GRID 256                // hist/scatter blocks
#define EPB (E_TOTAL / SORT_GRID)    // 6250 edges per sort block
#define GT_ROWS 128                  // u_gemm4 row tile

typedef short bf16x8 __attribute__((ext_vector_type(8)));
typedef float f32x4 __attribute__((ext_vector_type(4)));
typedef const __attribute__((address_space(1))) unsigned short* gas_t;
typedef __attribute__((address_space(3))) unsigned short* las_t;

__device__ __forceinline__ unsigned short f2bf(float f) {
    unsigned u = __float_as_uint(f);
    u += 0x7fff + ((u >> 16) & 1);   // round-to-nearest-even
    return (unsigned short)(u >> 16);
}
__device__ __forceinline__ float bf2f(unsigned short s) {
    return __uint_as_float((unsigned)s << 16);
}

// m204 bijective chunked XCD swizzle: consecutive output ids -> same XCD.
__device__ __forceinline__ int xcd_chunk(int orig, int nwg) {
    const int q = nwg >> 3, r = nwg & 7;
    const int x = orig & 7, s = orig >> 3;
    return (x < r ? x * (q + 1) : r * (q + 1) + (x - r) * q) + s;
}

// ---------------- cvt: h and W1 -> bf16 (+ atomic-free hist tail) ----------
// Blocks [0, nCvt): convert. Blocks [nCvt, nCvt+SORT_GRID): hist block k
// counts its 6250 edges' src buckets in LDS, stores cnt[k][b] (plain writes).
__global__ void cvt_kernel(const float* __restrict__ h, const float* __restrict__ w1,
                           unsigned short* __restrict__ hbf, unsigned short* __restrict__ w1bf,
                           int n4h, int n4w,
                           const int* __restrict__ srcE, int* __restrict__ cnt, int nCvt) {
    __shared__ int lh[NB2];
    const int tid = threadIdx.x;
    if ((int)blockIdx.x >= nCvt) {
        const int k = blockIdx.x - nCvt;
        const int base = k * EPB;
        if (tid < NB2) lh[tid] = 0;
        __syncthreads();
        for (int i = tid; i < EPB; i += 256)
            atomicAdd(&lh[srcE[base + i] >> 11], 1);   // LDS atomics only
        __syncthreads();
        if (tid < NB2) cnt[k * NB2 + tid] = lh[tid];
        return;
    }
    int i = blockIdx.x * blockDim.x + tid;
    if (i >= n4h + n4w) return;
    const float* s; unsigned short* d; int j;
    if (i < n4h) { s = h; d = hbf; j = i; }
    else { s = w1; d = w1bf; j = i - n4h; }
    float4 v = ((const float4*)s)[j];
    ushort4 o;
    o.x = f2bf(v.x); o.y = f2bf(v.y); o.z = f2bf(v.z); o.w = f2bf(v.w);
    ((ushort4*)d)[j] = o;
}

// ---------------- u_gemm v4: 128-row tiles, 2x work per DMA barrier --------
// blockIdx bx: tile = bx>>2 (128 node rows), half = (bx>>1)&1 (0: Us + b1,
// 1: Ud), nh = bx&1 (cols 0-127 vs 128-255 of the half's output).
// Wave w owns true cols n = nh*128 + w*32 + nt*16 + l15, nt in {0,1}.
__global__ __launch_bounds__(256, 3) void u_gemm4(
    const unsigned short* __restrict__ hbf,
    const unsigned short* __restrict__ w1bf,
    const float* __restrict__ b1,
    unsigned short* __restrict__ Us,
    unsigned short* __restrict__ Ud)
{
    __shared__ __align__(16) unsigned short A[GT_ROWS * 128];   // 32768 B

    const int tid = threadIdx.x;
    const int wave = tid >> 6;
    const int lane = tid & 63;
    const int l15 = lane & 15;
    const int quad = lane >> 4;

    const int tile = blockIdx.x >> 2;
    const int half = (blockIdx.x >> 1) & 1;
    const int nh = blockIdx.x & 1;
    const int r0 = tile * GT_ROWS;
    int rows = NNODES - r0; if (rows > GT_ROWS) rows = GT_ROWS;
    const int koff = half * 128;
    unsigned short* U = half ? Ud : Us;

    // --- issue async stage of A (32 KB), XOR swizzle c = p ^ (r&15) ---
#pragma unroll
    for (int it = 0; it < 8; ++it) {
        const int s = it * 256 + tid;      // 16B slot 0..2047
        const int r = s >> 4;              // row 0..127
        const int p = s & 15;              // position chunk
        const int c = p ^ (r & 15);        // content chunk
        if (r < rows)
            __builtin_amdgcn_global_load_lds(
                (gas_t)(hbf + (size_t)(r0 + r) * D + c * 8),
                (las_t)(A + it * 2048 + wave * 512), 16, 0, 0);
    }

    // --- B fragments + bias while DMA is in flight ---
    bf16x8 B[4][2];
    float bias[2];
#pragma unroll
    for (int nt = 0; nt < 2; ++nt) {
        const int n = nh * 128 + wave * 32 + nt * 16 + l15;
        bias[nt] = half ? 0.f : b1[n];
#pragma unroll
        for (int kit = 0; kit < 4; ++kit)
            B[kit][nt] = *(const bf16x8*)(w1bf + (size_t)n * K2 + koff + kit * 32 + quad * 8);
    }

    __syncthreads();   // vmcnt(0): A landed

    f32x4 acc[8][2];
    const f32x4 zero = {0.f, 0.f, 0.f, 0.f};
#pragma unroll
    for (int ms = 0; ms < 8; ++ms)
#pragma unroll
        for (int nt = 0; nt < 2; ++nt)
            acc[ms][nt] = zero;

#pragma unroll
    for (int kit = 0; kit < 4; ++kit) {
        const int p = (kit * 4 + quad) ^ l15;
#pragma unroll
        for (int ms = 0; ms < 8; ++ms) {
            const int row = ms * 16 + l15;
            const bf16x8 a = *(const bf16x8*)&A[row * 128 + p * 8];
#pragma unroll
            for (int nt = 0; nt < 2; ++nt)
                acc[ms][nt] = __builtin_amdgcn_mfma_f32_16x16x32_bf16(
                    a, B[kit][nt], acc[ms][nt], 0, 0, 0);
        }
    }

    // --- direct permuted store: dword per (ms,r), 64B segment per quad ---
    const int coff = nh * 128 + wave * 32 + l15 * 2;   // short offset in U row
#pragma unroll
    for (int ms = 0; ms < 8; ++ms) {
#pragma unroll
        for (int r = 0; r < 4; ++r) {
            const int m = ms * 16 + quad * 4 + r;
            if (m < rows) {
                const unsigned lo = f2bf(acc[ms][0][r] + bias[0]);
                const unsigned hi = f2bf(acc[ms][1][r] + bias[1]);
                *(unsigned*)(U + (size_t)(r0 + m) * H + coff) = lo | (hi << 16);
            }
        }
    }
}

// ---------------- scatter49: cnt-driven, coalesced packed scatter ----------
// Block k rebuilds (a) its within-bucket offset sum_{k'<k} cnt[k'][b] and
// (b) the global bucket prefix, from the cnt matrix (50 KB, L2-hot).
// Scatters edges as uint64 (src:17|dst:17) into sorted position p, and
// writes rank[e] = p (address coalesced) for the unscatter.
__global__ __launch_bounds__(256) void scatter49(
    const int* __restrict__ srcE, const int* __restrict__ dstE,
    const int* __restrict__ cnt,
    unsigned long long* __restrict__ pk, int* __restrict__ rank)
{
    __shared__ int pref[NB2];
    __shared__ int lcur[NB2];
    const int tid = threadIdx.x;
    const int k = blockIdx.x;
    const int base = k * EPB;

    if (tid < NB2) {
        int lb = 0, tot = 0;
        for (int kk = 0; kk < SORT_GRID; ++kk) {
            const int c = cnt[kk * NB2 + tid];
            if (kk < k) lb += c;
            tot += c;
        }
        lcur[tid] = lb;     // within-bucket offset of this block
        pref[tid] = tot;    // bucket total (prefixed below)
    }
    __syncthreads();
    if (tid == 0) {
        int s = 0;
        for (int b = 0; b < NB2; ++b) { const int t = pref[b]; pref[b] = s; s += t; }
    }
    __syncthreads();
    if (tid < NB2) lcur[tid] += pref[tid];
    __syncthreads();

    for (int i = tid; i < EPB; i += 256) {
        const int e = base + i;
        const int s = srcE[e];
        const int d = dstE[e];
        const int b = s >> 11;
        const int p = atomicAdd(&lcur[b], 1);
        pk[(size_t)p] = (unsigned long long)s | ((unsigned long long)d << 17);
        rank[e] = p;
    }
}

// ---------------- edge pass (sorted packed, coalesced writes) --------------
// U' layout: within each 32-col block, c'' = l15*2+nt holds n'' = nt*16+l15.
// 16-lane group handles 8 consecutive 4-edge chunks (32 sorted edges).
// Blocks xcd_chunk-swizzled: contiguous sorted ranges stay on one XCD ->
// each 1 MB src-bucket Us window is fetched ~once into that XCD's L2.
// Scores written COALESCED at the sorted position; unscatter permutes back.
__global__ __launch_bounds__(256) void edge_score_pk(
    const unsigned short* __restrict__ Us,
    const unsigned short* __restrict__ Ud,
    const unsigned long long* __restrict__ pk,
    const float* __restrict__ w2,
    const float* __restrict__ b2p,
    float* __restrict__ ssort)
{
    const int b = xcd_chunk(blockIdx.x, gridDim.x);
    const int tid = threadIdx.x;
    const int l = tid & 15;
    const int grp = b * 16 + (tid >> 4);   // 0..49999

    float w2v[16];
#pragma unroll
    for (int j = 0; j < 16; ++j) {
        const int cp = l * 16 + j;
        const int n = (cp & ~31) + ((cp & 1) << 4) + ((cp & 31) >> 1);
        w2v[j] = w2[n];
    }
    const float b2 = *b2p;

    const int g0 = grp * 8;
    for (int g = g0; g < g0 + 8; ++g) {
        const int e0 = g * 4;
        const uint4 pa = *(const uint4*)(pk + e0);       // edges 0,1
        const uint4 pb = *(const uint4*)(pk + e0 + 2);   // edges 2,3
        const unsigned lo[4] = {pa.x, pa.z, pb.x, pb.z};
        const unsigned hi[4] = {pa.y, pa.w, pb.y, pb.w};
        int sv[4], dv[4];
#pragma unroll
        for (int k = 0; k < 4; ++k) {
            sv[k] = lo[k] & 0x1FFFF;
            dv[k] = ((lo[k] >> 17) | (hi[k] << 15)) & 0x1FFFF;
        }

        bf16x8 u[4][2], v[4][2];
#pragma unroll
        for (int k = 0; k < 4; ++k) {
            const bf16x8* us = (const bf16x8*)(Us + (size_t)sv[k] * H + l * 16);
            const bf16x8* ud = (const bf16x8*)(Ud + (size_t)dv[k] * H + l * 16);
            u[k][0] = us[0]; u[k][1] = us[1];
            v[k][0] = ud[0]; v[k][1] = ud[1];
        }

        float4 res;
        float* resp = (float*)&res;
#pragma unroll
        for (int k = 0; k < 4; ++k) {
            float acc = 0.f;
#pragma unroll
            for (int j = 0; j < 8; ++j) {
                float hv = bf2f((unsigned short)u[k][0][j]) + bf2f((unsigned short)v[k][0][j]);
                acc = fmaf(fmaxf(hv, 0.f), w2v[j], acc);
            }
#pragma unroll
            for (int j = 0; j < 8; ++j) {
                float hv = bf2f((unsigned short)u[k][1][j]) + bf2f((unsigned short)v[k][1][j]);
                acc = fmaf(fmaxf(hv, 0.f), w2v[j + 8], acc);
            }
            acc += __shfl_xor(acc, 1, 16);
            acc += __shfl_xor(acc, 2, 16);
            acc += __shfl_xor(acc, 4, 16);
            acc += __shfl_xor(acc, 8, 16);
            resp[k] = acc + b2;
        }
        if (l == 0) *(float4*)(ssort + e0) = res;   // coalesced
    }
}

// ---------------- unscatter: out[e] = ssort[rank[e]] -----------------------
// Coalesced rank read, random dword READ over 6.4 MB (line-shared, no RFO),
// coalesced float4 out write.
__global__ __launch_bounds__(256) void unscatter(
    const float* __restrict__ ssort, const int* __restrict__ rank,
    float* __restrict__ out)
{
    const int g = blockIdx.x * 256 + threadIdx.x;   // 4-edge group
    if (g >= E_TOTAL / 4) return;
    const int e0 = g * 4;
    const int4 r4 = *(const int4*)(rank + e0);
    float4 o;
    o.x = ssort[r4.x];
    o.y = ssort[r4.y];
    o.z = ssort[r4.z];
    o.w = ssort[r4.w];
    *(float4*)(out + e0) = o;
}

// ---------------- edge pass (R12 unsorted, mid-ws fallback) ----------------
__global__ __launch_bounds__(256) void edge_score(
    const unsigned short* __restrict__ Us,
    const unsigned short* __restrict__ Ud,
    const int* __restrict__ srcE,
    const int* __restrict__ dstE,
    const float* __restrict__ w2,
    const float* __restrict__ b2p,
    float* __restrict__ out)
{
    const int gt = blockIdx.x * 256 + threadIdx.x;
    const int l = gt & 15;
    const int q = gt >> 4;
    const int Q = (gridDim.x * 256) >> 4;
    const int NGRP = E_TOTAL / 4;   // 400000

    float w2v[16];
#pragma unroll
    for (int j = 0; j < 16; ++j) {
        const int cp = l * 16 + j;
        const int n = (cp & ~31) + ((cp & 1) << 4) + ((cp & 31) >> 1);
        w2v[j] = w2[n];
    }
    const float b2 = *b2p;

    for (int g = q; g < NGRP; g += Q) {
        const int e0 = g * 4;
        const int4 s4 = *(const int4*)(srcE + e0);
        const int4 d4 = *(const int4*)(dstE + e0);
        const int sv[4] = {s4.x, s4.y, s4.z, s4.w};
        const int dv[4] = {d4.x, d4.y, d4.z, d4.w};

        bf16x8 u[4][2], v[4][2];
#pragma unroll
        for (int k = 0; k < 4; ++k) {
            const bf16x8* us = (const bf16x8*)(Us + (size_t)sv[k] * H + l * 16);
            const bf16x8* ud = (const bf16x8*)(Ud + (size_t)dv[k] * H + l * 16);
            u[k][0] = us[0]; u[k][1] = us[1];
            v[k][0] = ud[0]; v[k][1] = ud[1];
        }

        float4 res;
        float* resp = (float*)&res;
#pragma unroll
        for (int k = 0; k < 4; ++k) {
            float acc = 0.f;
#pragma unroll
            for (int j = 0; j < 8; ++j) {
                float hv = bf2f((unsigned short)u[k][0][j]) + bf2f((unsigned short)v[k][0][j]);
                acc = fmaf(fmaxf(hv, 0.f), w2v[j], acc);
            }
#pragma unroll
            for (int j = 0; j < 8; ++j) {
                float hv = bf2f((unsigned short)u[k][1][j]) + bf2f((unsigned short)v[k][1][j]);
                acc = fmaf(fmaxf(hv, 0.f), w2v[j + 8], acc);
            }
            acc += __shfl_xor(acc, 1, 16);
            acc += __shfl_xor(acc, 2, 16);
            acc += __shfl_xor(acc, 4, 16);
            acc += __shfl_xor(acc, 8, 16);
            resp[k] = acc + b2;
        }
        if (l == 0) *(float4*)(out + e0) = res;
    }
}

// ======================= R4 fallback (ws too small) ======================

#define TILE_M 32
#define NTILES (E_TOTAL / TILE_M)
#define GRID 2500

#if defined(__has_attribute)
#if __has_attribute(amdgpu_waves_per_eu)
#define LB __launch_bounds__(256) __attribute__((amdgpu_waves_per_eu(2, 2)))
#else
#define LB __launch_bounds__(256, 2)
#endif
#else
#define LB __launch_bounds__(256, 2)
#endif

__global__ LB void edge_mlp(
    const unsigned short* __restrict__ hbf,
    const int* __restrict__ srcE,
    const int* __restrict__ dstE,
    const unsigned short* __restrict__ w1bf,
    const float* __restrict__ b1,
    const float* __restrict__ w2,
    const float* __restrict__ b2p,
    float* __restrict__ out)
{
    __shared__ __align__(16) unsigned short X[2][TILE_M * K2];
    __shared__ float red[2][TILE_M][5];

    const int tid = threadIdx.x;
    const int wave = tid >> 6;
    const int lane = tid & 63;
    const int lane15 = lane & 15;
    const int quad = lane >> 4;

    bf16x8 B[8][4];
#pragma unroll
    for (int kit = 0; kit < 8; ++kit)
#pragma unroll
        for (int nt = 0; nt < 4; ++nt) {
            int n = wave * 64 + nt * 16 + lane15;
            int k = kit * 32 + quad * 8;
            B[kit][nt] = *(const bf16x8*)(w1bf + n * K2 + k);
        }

    float b1v[4], w2v[4];
#pragma unroll
    for (int nt = 0; nt < 4; ++nt) {
        int n = wave * 64 + nt * 16 + lane15;
        b1v[nt] = b1[n];
        w2v[nt] = w2[n];
    }
    const float b2 = *b2p;

    const int r_off = tid >> 5;
    const int c = (tid & 31) ^ (r_off & 7);
    const int half = c >> 4;
    const int fc = c & 15;
    const int* idx_base = half ? dstE : srcE;
    const int gshort = fc * 8;

    const int t0 = blockIdx.x;
    int inode[4];

#pragma unroll
    for (int it = 0; it < 4; ++it)
        inode[it] = idx_base[t0 * TILE_M + it * 8 + r_off];
#pragma unroll
    for (int it = 0; it < 4; ++it)
        __builtin_amdgcn_global_load_lds(
            (gas_t)(hbf + inode[it] * D + gshort),
            (las_t)(&X[0][0] + it * 2048 + wave * 512), 16, 0, 0);
    {
        const int t1 = t0 + GRID;
#pragma unroll
        for (int it = 0; it < 4; ++it)
            inode[it] = idx_base[t1 * TILE_M + it * 8 + r_off];
    }

    int buf = 0;
    int prev_eb = -1;

    for (int tile = t0; tile < NTILES; tile += GRID) {
        __syncthreads();

        const int nt1 = tile + GRID;
        if (nt1 < NTILES) {
            unsigned short* Xn = &X[buf ^ 1][0];
#pragma unroll
            for (int it = 0; it < 4; ++it)
                __builtin_amdgcn_global_load_lds(
                    (gas_t)(hbf + inode[it] * D + gshort),
                    (las_t)(Xn + it * 2048 + wave * 512), 16, 0, 0);
        }
        const int nt2 = tile + 2 * GRID;
        if (nt2 < NTILES) {
            const int eb2 = nt2 * TILE_M;
#pragma unroll
            for (int it = 0; it < 4; ++it)
                inode[it] = idx_base[eb2 + it * 8 + r_off];
        }
        if (prev_eb >= 0 && tid < TILE_M) {
            float s = b2;
#pragma unroll
            for (int w = 0; w < 4; ++w) s += red[buf ^ 1][tid][w];
            out[prev_eb + tid] = s;
        }

        const unsigned short* Xc = &X[buf][0];
        f32x4 acc[2][4];
        const f32x4 zero = {0.f, 0.f, 0.f, 0.f};
#pragma unroll
        for (int ms = 0; ms < 2; ++ms)
#pragma unroll
            for (int nt = 0; nt < 4; ++nt)
                acc[ms][nt] = zero;

#pragma unroll
        for (int kit = 0; kit < 8; ++kit) {
            const int p8 = (((kit * 4 + quad) ^ (lane15 & 7))) * 8;
            bf16x8 a[2];
#pragma unroll
            for (int ms = 0; ms < 2; ++ms)
                a[ms] = *(const bf16x8*)&Xc[(ms * 16 + lane15) * K2 + p8];
#pragma unroll
            for (int ms = 0; ms < 2; ++ms)
#pragma unroll
                for (int nt = 0; nt < 4; ++nt)
                    acc[ms][nt] = __builtin_amdgcn_mfma_f32_16x16x32_bf16(
                        a[ms], B[kit][nt], acc[ms][nt], 0, 0, 0);
        }

#pragma unroll
        for (int ms = 0; ms < 2; ++ms)
#pragma unroll
            for (int r = 0; r < 4; ++r) {
                float p = 0.f;
#pragma unroll
                for (int nt = 0; nt < 4; ++nt) {
                    float hv = acc[ms][nt][r] + b1v[nt];
                    p = fmaf(fmaxf(hv, 0.f), w2v[nt], p);
                }
                p += __shfl_xor(p, 1, 16);
                p += __shfl_xor(p, 2, 16);
                p += __shfl_xor(p, 4, 16);
                p += __shfl_xor(p, 8, 16);
                if (lane15 == 0) red[buf][ms * 16 + quad * 4 + r][wave] = p;
            }
        prev_eb = tile * TILE_M;
        buf ^= 1;
    }

    __syncthreads();
    if (prev_eb >= 0 && tid < TILE_M) {
        float s = b2;
#pragma unroll
        for (int w = 0; w < 4; ++w) s += red[buf ^ 1][tid][w];
        out[prev_eb + tid] = s;
    }
}

// ================================ launch ================================

extern "C" void kernel_launch(void* const* d_in, const int* in_sizes, int n_in,
                              void* d_out, int out_size, void* d_ws, size_t ws_size,
                              hipStream_t stream) {
    const float* h    = (const float*)d_in[0];
    const int*   srcE = (const int*)d_in[1];
    const int*   dstE = (const int*)d_in[2];
    const float* W1   = (const float*)d_in[3];
    const float* b1   = (const float*)d_in[4];
    const float* w2   = (const float*)d_in[5];
    const float* b2   = (const float*)d_in[6];
    float* out = (float*)d_out;

    char* ws = (char*)d_ws;
    const size_t offUs   = 0;                        // 51,200,000 B
    const size_t offUd   = 51200000;                 // 51,200,000 B
    const size_t offHbf  = 102400000;                // 25,600,000 B
    const size_t offW1bf = 128000000;                // 131,072 B
    const size_t need    = offW1bf + 131072;         // 128,131,072 B
    // R19 sort extras (rank/ssort alias the dead hbf region after u_gemm4)
    const size_t offCnt  = need;                     // 256*49 ints (pad 65536)
    const size_t offPK   = offCnt + 65536;           // 12,800,000 B (uint64/edge)
    const size_t need2   = offPK + 12800000;         // 140,996,608 B

    if (ws_size >= need) {
        unsigned short* Us   = (unsigned short*)(ws + offUs);
        unsigned short* Ud   = (unsigned short*)(ws + offUd);
        unsigned short* hbf  = (unsigned short*)(ws + offHbf);
        unsigned short* w1bf = (unsigned short*)(ws + offW1bf);
        const bool sorted = (ws_size >= need2);
        int* cnt = (int*)(ws + offCnt);
        unsigned long long* pk = (unsigned long long*)(ws + offPK);
        // reuse dead hbf region: rank (6.4 MB) + score_sorted (6.4 MB) <= 25.6 MB
        int*   rank  = (int*)(ws + offHbf);
        float* ssort = (float*)(ws + offHbf + 6400000);

        int n4h = NNODES * D / 4, n4w = H * K2 / 4;
        const int nCvt = (n4h + n4w + 255) / 256;
        const int cvtGrid = nCvt + (sorted ? SORT_GRID : 0);
        cvt_kernel<<<cvtGrid, 256, 0, stream>>>(
            h, W1, hbf, w1bf, n4h, n4w, srcE, cnt, nCvt);
        u_gemm4<<<4 * ((NNODES + GT_ROWS - 1) / GT_ROWS), 256, 0, stream>>>(
            hbf, w1bf, b1, Us, Ud);
        if (sorted) {
            scatter49<<<SORT_GRID, 256, 0, stream>>>(srcE, dstE, cnt, pk, rank);
            edge_score_pk<<<EDGE_GRID, 256, 0, stream>>>(Us, Ud, pk, w2, b2, ssort);
            unscatter<<<(E_TOTAL / 4 + 255) / 256, 256, 0, stream>>>(ssort, rank, out);
        } else {
            edge_score<<<4096, 256, 0, stream>>>(Us, Ud, srcE, dstE, w2, b2, out);
        }
    } else {
        unsigned short* hbf  = (unsigned short*)d_ws;
        unsigned short* w1bf = hbf + (size_t)NNODES * D;
        int n4h = NNODES * D / 4, n4w = H * K2 / 4;
        cvt_kernel<<<(n4h + n4w + 255) / 256, 256, 0, stream>>>(
            h, W1, hbf, w1bf, n4h, n4w, nullptr, nullptr, (n4h + n4w + 255) / 256);
        edge_mlp<<<GRID, 256, 0, stream>>>(hbf, srcE, dstE, w1bf, b1, w2, b2, out);
    }
}